// Round 1
// baseline (270.850 us; speedup 1.0000x reference)
//
#include <hip/hip_runtime.h>
#include <hip/hip_bf16.h>
#include <stdint.h>

#define BM 64
#define BN 128
#define BD 32
#define NTHREADS 256

// ---------------- c2 pre-kernel: halfc2[k] = 0.5 * sum_d cb[k][d]^2 ----------------
__global__ __launch_bounds__(256) void vq_c2_kernel(const float* __restrict__ cb,
                                                    float* __restrict__ halfc2) {
  int row  = blockIdx.x * 4 + (threadIdx.x >> 6);
  int lane = threadIdx.x & 63;
  float4 v = *reinterpret_cast<const float4*>(cb + (size_t)row * 256 + lane * 4);
  float s = v.x * v.x + v.y * v.y + v.z * v.z + v.w * v.w;
#pragma unroll
  for (int m = 32; m >= 1; m >>= 1) s += __shfl_xor(s, m, 64);
  if (lane == 0) halfc2[row] = 0.5f * s;
}

// async global->LDS, 16B per lane
__device__ __forceinline__ void glds16(const float* g, float* l) {
  __builtin_amdgcn_global_load_lds(
      (const __attribute__((address_space(1))) void*)g,
      (__attribute__((address_space(3))) void*)l, 16, 0, 0);
}

// ---------------- main kernel: fused GEMM + argmax(x.c - 0.5*|c|^2) ----------------
__global__ __launch_bounds__(NTHREADS, 2) void vq_argmin_kernel(
    const float* __restrict__ x, const float* __restrict__ cb,
    const float* __restrict__ halfc2, int* __restrict__ out) {
  __shared__ float lds[2][BM * BD + BN * BD];  // 2 x 24KB
  __shared__ float c2s[1024];                  // 4KB

  const int tid = threadIdx.x;
  const int r0  = blockIdx.x * BM;

  // cache halfc2 in LDS (visible after first pipeline barrier+lgkmcnt drain)
  {
    float4 v = reinterpret_cast<const float4*>(halfc2)[tid];
    reinterpret_cast<float4*>(c2s)[tid] = v;
  }

  const int tc = tid & 15;   // code group 0..15
  const int tr = tid >> 4;   // row group 0..15
  const int sA = 4 * (tr & 7);  // dword XOR swizzle for this thread's rows
  const int sB = 4 * (tc & 7);  // dword XOR swizzle for this thread's codes

  float bestv[4];
  int   besti[4];
#pragma unroll
  for (int i = 0; i < 4; ++i) { bestv[i] = -3.4e38f; besti[i] = 0; }

  auto stage = [&](int n0, int d0, int p) {
    float* bufA = &lds[p][0];
    float* bufB = &lds[p][BM * BD];
    // A tile: 64 rows x 32 d = 8KB -> 2 rounds of 256 lanes x 16B
#pragma unroll
    for (int r = 0; r < 2; ++r) {
      int t2  = r * 256 + tid;
      int row = t2 >> 3;
      int dq  = (t2 & 7) << 2;                    // dest dword within row
      int dg  = dq ^ (4 * ((row >> 2) & 7));      // pre-swizzled source dword
      glds16(x + (size_t)(r0 + row) * 256 + d0 + dg, bufA + row * BD + dq);
    }
    // B tile: 128 codes x 32 d = 16KB -> 4 rounds
#pragma unroll
    for (int r = 0; r < 4; ++r) {
      int t2   = r * 256 + tid;
      int code = t2 >> 3;
      int dq   = (t2 & 7) << 2;
      int dg   = dq ^ (4 * ((code >> 2) & 7));
      glds16(cb + (size_t)(n0 + code) * 256 + d0 + dg, bufB + code * BD + dq);
    }
  };

  stage(0, 0, 0);  // prologue: 6 glds in flight

  for (int nt = 0; nt < 8; ++nt) {
    float acc[4][8];
#pragma unroll
    for (int i = 0; i < 4; ++i)
#pragma unroll
      for (int j = 0; j < 8; ++j) acc[i][j] = 0.f;

    for (int dt = 0; dt < 8; ++dt) {
      const int t = nt * 8 + dt;
      const int p = t & 1;
      if (t < 63) {
        const int t1 = t + 1;
        stage((t1 >> 3) * BN, (t1 & 7) * BD, p ^ 1);
        // counted wait: 6 newest (next stage) may stay in flight; the 6 for
        // stage t (issued last iteration) are guaranteed complete.
        asm volatile("s_waitcnt vmcnt(6)" ::: "memory");
      } else {
        asm volatile("s_waitcnt vmcnt(0)" ::: "memory");
      }
      __builtin_amdgcn_s_barrier();

      const float* bufA = &lds[p][0];
      const float* bufB = &lds[p][BM * BD];
#pragma unroll
      for (int d = 0; d < BD; d += 4) {
        float4 a[4], b[8];
#pragma unroll
        for (int i = 0; i < 4; ++i)
          a[i] = *reinterpret_cast<const float4*>(&bufA[(tr * 4 + i) * BD + (d ^ sA)]);
#pragma unroll
        for (int j = 0; j < 4; ++j) {
          b[j]     = *reinterpret_cast<const float4*>(&bufB[(tc * 4 + j) * BD + (d ^ sB)]);
          b[j + 4] = *reinterpret_cast<const float4*>(&bufB[(64 + tc * 4 + j) * BD + (d ^ sB)]);
        }
#pragma unroll
        for (int i = 0; i < 4; ++i)
#pragma unroll
          for (int j = 0; j < 8; ++j) {
            acc[i][j] = fmaf(a[i].x, b[j].x, acc[i][j]);
            acc[i][j] = fmaf(a[i].y, b[j].y, acc[i][j]);
            acc[i][j] = fmaf(a[i].z, b[j].z, acc[i][j]);
            acc[i][j] = fmaf(a[i].w, b[j].w, acc[i][j]);
          }
      }
      // drain this wave's LDS reads before anyone overwrites this buffer
      asm volatile("s_waitcnt lgkmcnt(0)" ::: "memory");
      __builtin_amdgcn_s_barrier();
    }

    // fold in -0.5*|c|^2 and update running argmax for this 128-code chunk
    const int n0 = nt * BN;
#pragma unroll
    for (int j = 0; j < 8; ++j) {
      const int cj = (j < 4) ? (tc * 4 + j) : (64 + tc * 4 + (j - 4));
      const float hc = c2s[n0 + cj];
#pragma unroll
      for (int i = 0; i < 4; ++i) {
        float s = acc[i][j] - hc;
        if (s > bestv[i]) { bestv[i] = s; besti[i] = n0 + cj; }  // strict > keeps first index
      }
    }
  }

  // tournament across the 16 code-groups (lanes differing in tc bits, same wave)
#pragma unroll
  for (int i = 0; i < 4; ++i) {
#pragma unroll
    for (int m = 1; m < 16; m <<= 1) {
      float ov = __shfl_xor(bestv[i], m, 64);
      int   oi = __shfl_xor(besti[i], m, 64);
      if (ov > bestv[i] || (ov == bestv[i] && oi < besti[i])) { bestv[i] = ov; besti[i] = oi; }
    }
    if (tc == 0) out[r0 + tr * 4 + i] = besti[i];
  }
}

extern "C" void kernel_launch(void* const* d_in, const int* in_sizes, int n_in,
                              void* d_out, int out_size, void* d_ws, size_t ws_size,
                              hipStream_t stream) {
  const float* x  = (const float*)d_in[0];   // (8,4096,256) fp32
  const float* cb = (const float*)d_in[1];   // (1024,256) fp32
  int* out   = (int*)d_out;                  // (8,4096) int32
  float* c2  = (float*)d_ws;                 // 1024 floats scratch

  hipLaunchKernelGGL(vq_c2_kernel, dim3(256), dim3(256), 0, stream, cb, c2);
  hipLaunchKernelGGL(vq_argmin_kernel, dim3(512), dim3(NTHREADS), 0, stream,
                     x, cb, c2, out);
}

// Round 2
// 233.765 us; speedup vs baseline: 1.1586x; 1.1586x over previous
//
#include <hip/hip_runtime.h>
#include <stdint.h>

#define BM 128
#define BN 256
#define BD 32
#define NT 512

// ---------------- c2 pre-kernel: halfc2[k] = 0.5 * sum_d cb[k][d]^2 ----------------
__global__ __launch_bounds__(256) void vq_c2_kernel(const float* __restrict__ cb,
                                                    float* __restrict__ halfc2) {
  int row  = blockIdx.x * 4 + (threadIdx.x >> 6);
  int lane = threadIdx.x & 63;
  float4 v = *reinterpret_cast<const float4*>(cb + (size_t)row * 256 + lane * 4);
  float s = v.x * v.x + v.y * v.y + v.z * v.z + v.w * v.w;
#pragma unroll
  for (int m = 32; m >= 1; m >>= 1) s += __shfl_xor(s, m, 64);
  if (lane == 0) halfc2[row] = 0.5f * s;
}

// async global->LDS, 16B per lane
__device__ __forceinline__ void glds16(const float* g, float* l) {
  __builtin_amdgcn_global_load_lds(
      (const __attribute__((address_space(1))) void*)g,
      (__attribute__((address_space(3))) void*)l, 16, 0, 0);
}

// ---------------- main kernel: fused GEMM + argmax(x.c - 0.5*|c|^2) ----------------
// 512 threads = 8 waves. Thread (tr=tid>>5, tc=tid&31) owns rows tr*8+i, codes tc*8+j.
// Per block: 128 rows x all 1024 codes (4 chunks of BN=256), K=256 in BD=32 steps.
// LDS layout: [row][32 dwords], 4-dword chunks XOR-swizzled by (row>>3)&7.
__global__ __launch_bounds__(NT, 2) void vq_argmin_kernel(
    const float* __restrict__ x, const float* __restrict__ cb,
    const float* __restrict__ halfc2, int* __restrict__ out) {
  __shared__ float lds[2][(BM + BN) * BD];  // 2 x 48KB
  __shared__ float c2s[1024];               // 4KB

  const int tid = threadIdx.x;
  const int w   = tid >> 6;    // wave id 0..7
  const int tc  = tid & 31;    // code group 0..31
  const int tr  = tid >> 5;    // row group 0..15
  const int r0  = blockIdx.x * BM;

  // cache halfc2 in LDS (visible after first barrier)
  reinterpret_cast<float2*>(c2s)[tid] = reinterpret_cast<const float2*>(halfc2)[tid];

  const int sA  = tr & 7;        // stored-chunk xor for this thread's A rows (row>>3 == tr)
  const int sB  = tc & 7;        // stored-chunk xor for this thread's B rows (code>>3 == tc)
  const int sAB = sA ^ sB;

  // staging lane constants: dest = buf + t2*16B (linear), src chunk pre-swizzled.
  // For every round, (row>>3)&7 == wave id, so source chunk = (tid&7) ^ w.
  const int cho = (((tid & 7) ^ w)) * 4;  // dword offset within the BD chunk
  const int sub = tid >> 3;               // row-within-round 0..63

  float bestv[8];
  int   besti[8];
#pragma unroll
  for (int i = 0; i < 8; ++i) { bestv[i] = -3.4e38f; besti[i] = 0; }

  auto stage = [&](int n0, int d0, int p) {
    float* dst  = &lds[p][0];
    float* dstB = dst + BM * BD;
#pragma unroll
    for (int r = 0; r < 2; ++r) {  // A: 128 rows x 32 dw = 2 rounds
      int t2 = r * NT + tid;
      glds16(x + (size_t)(r0 + r * 64 + sub) * 256 + d0 + cho, dst + t2 * 4);
    }
#pragma unroll
    for (int r = 0; r < 4; ++r) {  // B: 256 codes x 32 dw = 4 rounds
      int t2 = r * NT + tid;
      glds16(cb + (size_t)(n0 + r * 64 + sub) * 256 + d0 + cho, dstB + t2 * 4);
    }
  };

  stage(0, 0, 0);  // prologue: 6 glds in flight

  int t = 0;
  for (int nt = 0; nt < 4; ++nt) {
    float acc[8][8];
#pragma unroll
    for (int i = 0; i < 8; ++i)
#pragma unroll
      for (int j = 0; j < 8; ++j) acc[i][j] = 0.f;

    for (int dt = 0; dt < 8; ++dt, ++t) {
      const int p = t & 1;
      if (t < 31) {
        const int t1 = t + 1;
        stage((t1 >> 3) * BN, (t1 & 7) * BD, t1 & 1);
        // 6 newest (next stage) stay in flight; stage t's 6 are complete.
        asm volatile("s_waitcnt vmcnt(6)" ::: "memory");
      } else {
        asm volatile("s_waitcnt vmcnt(0)" ::: "memory");
      }
      __builtin_amdgcn_s_barrier();

      const float* pA = &lds[p][tr * 8 * BD];
      const float* pB = &lds[p][BM * BD + tc * 8 * BD];
#pragma unroll
      for (int cc = 0; cc < 8; ++cc) {  // iterate STORED chunks: A offsets are immediates
        const float* pBc = pB + ((cc ^ sAB) << 2);
        float4 a[8], b[8];
#pragma unroll
        for (int i = 0; i < 8; ++i)
          a[i] = *reinterpret_cast<const float4*>(pA + i * BD + cc * 4);
#pragma unroll
        for (int j = 0; j < 8; ++j)
          b[j] = *reinterpret_cast<const float4*>(pBc + j * BD);
#pragma unroll
        for (int i = 0; i < 8; ++i)
#pragma unroll
          for (int j = 0; j < 8; ++j) {
            acc[i][j] = fmaf(a[i].x, b[j].x, acc[i][j]);
            acc[i][j] = fmaf(a[i].y, b[j].y, acc[i][j]);
            acc[i][j] = fmaf(a[i].z, b[j].z, acc[i][j]);
            acc[i][j] = fmaf(a[i].w, b[j].w, acc[i][j]);
          }
      }
      asm volatile("s_waitcnt lgkmcnt(0)" ::: "memory");
      __builtin_amdgcn_s_barrier();
    }

    // fold -0.5*|c|^2, update running argmax (codes ascending -> strict > keeps first)
    const int n0 = nt * BN;
#pragma unroll
    for (int j = 0; j < 8; ++j) {
      const int code = n0 + tc * 8 + j;
      const float hc = c2s[code];
#pragma unroll
      for (int i = 0; i < 8; ++i) {
        float s = acc[i][j] - hc;
        if (s > bestv[i]) { bestv[i] = s; besti[i] = code; }
      }
    }
  }

  // tournament across the 32 code-groups (tc = lane bits 0..4, same tr half-wave)
#pragma unroll
  for (int i = 0; i < 8; ++i) {
#pragma unroll
    for (int m = 1; m <= 16; m <<= 1) {
      float ov = __shfl_xor(bestv[i], m, 64);
      int   oi = __shfl_xor(besti[i], m, 64);
      if (ov > bestv[i] || (ov == bestv[i] && oi < besti[i])) { bestv[i] = ov; besti[i] = oi; }
    }
  }
  if (tc == 0) {
#pragma unroll
    for (int i = 0; i < 8; ++i) out[r0 + tr * 8 + i] = besti[i];
  }
}

extern "C" void kernel_launch(void* const* d_in, const int* in_sizes, int n_in,
                              void* d_out, int out_size, void* d_ws, size_t ws_size,
                              hipStream_t stream) {
  const float* x  = (const float*)d_in[0];   // (8,4096,256) fp32
  const float* cb = (const float*)d_in[1];   // (1024,256) fp32
  int* out   = (int*)d_out;                  // (8,4096) int32
  float* c2  = (float*)d_ws;                 // 1024 floats scratch

  hipLaunchKernelGGL(vq_c2_kernel, dim3(256), dim3(256), 0, stream, cb, c2);
  hipLaunchKernelGGL(vq_argmin_kernel, dim3(32768 / BM), dim3(NT), 0, stream,
                     x, cb, c2, out);
}